// Round 1
// baseline (295.523 us; speedup 1.0000x reference)
//
#include <hip/hip_runtime.h>

#define NF 64
#define ND 32
#define NPAIR 2016   // 64*63/2
#define GSTR 68      // gram LDS row stride (floats): (4i+j)%32 -> 2-way max on tile writes

// One block per sample. 256 threads = 16x16 grid of 4x4 gram tiles.
__global__ __launch_bounds__(256, 4) void ip_gram_kernel(
    const float* __restrict__ in, float* __restrict__ out) {

    __shared__ float xt[ND][NF];        // transposed sample: xt[d][f]  (8 KiB)
    __shared__ float gram[NF][GSTR];    // full gram, padded (17.4 KiB)

    const int t = threadIdx.x;
    const int s = blockIdx.x;
    const float* src = in + (size_t)s * (NF * ND);

    // ---- stage global -> LDS (transposed). 512 float4 loads, coalesced. ----
    #pragma unroll
    for (int it = 0; it < 2; ++it) {
        int idx4 = t + it * 256;            // float4 index 0..511
        float4 v = ((const float4*)src)[idx4];
        int n = idx4 << 2;                  // flat element index
        int f = n >> 5;                     // field
        int d = n & 31;                     // dim (multiple of 4)
        xt[d + 0][f] = v.x;
        xt[d + 1][f] = v.y;
        xt[d + 2][f] = v.z;
        xt[d + 3][f] = v.w;
    }
    __syncthreads();

    // ---- compute 4x4 tile: rows i = 4*ty.., cols j = 4*tx.. ----
    const int tx = t & 15;
    const int ty = t >> 4;
    float acc[4][4] = {{0.f}};

    #pragma unroll 8
    for (int d = 0; d < ND; ++d) {
        // i-side: 16 lanes share each address (broadcast, conflict-free)
        float4 a = *(const float4*)&xt[d][ty << 2];
        // j-side: 16 distinct addresses over 64 floats -> 2-way (free)
        float4 b = *(const float4*)&xt[d][tx << 2];
        acc[0][0] += a.x * b.x; acc[0][1] += a.x * b.y; acc[0][2] += a.x * b.z; acc[0][3] += a.x * b.w;
        acc[1][0] += a.y * b.x; acc[1][1] += a.y * b.y; acc[1][2] += a.y * b.z; acc[1][3] += a.y * b.w;
        acc[2][0] += a.z * b.x; acc[2][1] += a.z * b.y; acc[2][2] += a.z * b.z; acc[2][3] += a.z * b.w;
        acc[3][0] += a.w * b.x; acc[3][1] += a.w * b.y; acc[3][2] += a.w * b.z; acc[3][3] += a.w * b.w;
    }

    // ---- dump tile to LDS gram ----
    #pragma unroll
    for (int r = 0; r < 4; ++r) {
        *(float4*)&gram[(ty << 2) + r][tx << 2] =
            make_float4(acc[r][0], acc[r][1], acc[r][2], acc[r][3]);
    }
    __syncthreads();

    // ---- coalesced upper-triangle write: pair p -> (i,j), i<j ----
    // base(i) = i*(127-i)/2 ; p = base(i) + (j - i - 1)
    float* dst = out + (size_t)s * NPAIR;
    #pragma unroll
    for (int k = 0; k < 8; ++k) {
        int p = t + (k << 8);
        if (p < NPAIR) {
            int i = (int)((127.0f - sqrtf(16129.0f - 8.0f * (float)p)) * 0.5f);
            if (i < 0) i = 0;
            if (i > 62) i = 62;
            // fix up float rounding
            while (i < 62 && (((i + 1) * (126 - i)) >> 1) <= p) ++i;
            while (i > 0 && ((i * (127 - i)) >> 1) > p) --i;
            int base = (i * (127 - i)) >> 1;
            int j = i + 1 + (p - base);
            dst[p] = gram[i][j];
        }
    }
}

extern "C" void kernel_launch(void* const* d_in, const int* in_sizes, int n_in,
                              void* d_out, int out_size, void* d_ws, size_t ws_size,
                              hipStream_t stream) {
    const float* in = (const float*)d_in[0];
    float* out = (float*)d_out;
    const int nsamples = in_sizes[0] / (NF * ND);   // 16384
    ip_gram_kernel<<<nsamples, 256, 0, stream>>>(in, out);
}

// Round 2
// 234.046 us; speedup vs baseline: 1.2627x; 1.2627x over previous
//
#include <hip/hip_runtime.h>

#define NF 64
#define ND 32
#define NPAIR 2016
#define XSTR 68                    // xt row stride (floats): 4-way max staging, 2-way compute reads
#define SAMP_FLOATS (ND * XSTR)    // 2176 floats per sample; flat gram (2016) aliases this

// 256 threads = 4 waves; each wave owns one sample. 8x8 lane grid x 8x8 register tile.
__global__ __launch_bounds__(256, 4) void ip_gram_kernel(
    const float* __restrict__ in, float* __restrict__ out) {

    __shared__ float smem[4 * SAMP_FLOATS];   // 34816 B -> 4 blocks/CU, 16 waves/CU

    const int t = threadIdx.x;
    const int w = t >> 6;            // wave id 0..3
    const int l = t & 63;            // lane
    const int s = blockIdx.x * 4 + w;

    float* xt = smem + w * SAMP_FLOATS;          // transposed sample: xt[d*XSTR + f]
    const float* src = in + (size_t)s * (NF * ND);

    // ---- stage: coalesced float4 global loads -> transposed LDS ----
    #pragma unroll
    for (int it = 0; it < 8; ++it) {
        int idx4 = l + (it << 6);          // float4 index 0..511
        float4 v = ((const float4*)src)[idx4];
        int f  = idx4 >> 3;                // field (32 floats = 8 float4 per field)
        int d0 = (idx4 & 7) << 2;          // dim base
        xt[(d0 + 0) * XSTR + f] = v.x;
        xt[(d0 + 1) * XSTR + f] = v.y;
        xt[(d0 + 2) * XSTR + f] = v.z;
        xt[(d0 + 3) * XSTR + f] = v.w;
    }
    __syncthreads();

    // ---- compute: 8x8 tile per lane, rows 8*ty.., cols 8*tx.. ----
    const int tx = l & 7;
    const int ty = l >> 3;
    float acc[8][8];
    #pragma unroll
    for (int r = 0; r < 8; ++r)
        #pragma unroll
        for (int c = 0; c < 8; ++c) acc[r][c] = 0.f;

    #pragma unroll 8
    for (int d = 0; d < ND; ++d) {
        const float* row = xt + d * XSTR;
        float4 a0 = *(const float4*)(row + (ty << 3));
        float4 a1 = *(const float4*)(row + (ty << 3) + 4);
        float4 b0 = *(const float4*)(row + (tx << 3));
        float4 b1 = *(const float4*)(row + (tx << 3) + 4);
        float a[8] = {a0.x, a0.y, a0.z, a0.w, a1.x, a1.y, a1.z, a1.w};
        float b[8] = {b0.x, b0.y, b0.z, b0.w, b1.x, b1.y, b1.z, b1.w};
        #pragma unroll
        for (int r = 0; r < 8; ++r)
            #pragma unroll
            for (int c = 0; c < 8; ++c)
                acc[r][c] += a[r] * b[c];
    }
    __syncthreads();

    // ---- scatter upper-triangle into flat-packed gram (aliases xt space) ----
    // p(i,j) = i*(127-i)/2 + (j-i-1); per r the 8 c-values are contiguous.
    float* g = xt;
    #pragma unroll
    for (int r = 0; r < 8; ++r) {
        int i  = (ty << 3) + r;
        int P0 = ((i * (127 - i)) >> 1) - i - 1 + (tx << 3);
        #pragma unroll
        for (int c = 0; c < 8; ++c) {
            int j = (tx << 3) + c;
            if (j > i) g[P0 + c] = acc[r][c];
        }
    }
    __syncthreads();

    // ---- coalesced gather + float4 global stores (2016 = 504 float4, 16B-aligned) ----
    float* dst = out + (size_t)s * NPAIR;
    #pragma unroll
    for (int k = 0; k < 8; ++k) {
        int idx4 = (k << 6) + l;
        if (idx4 < 504) {
            float4 v = *(const float4*)(g + (idx4 << 2));
            *(float4*)(dst + (idx4 << 2)) = v;
        }
    }
}

extern "C" void kernel_launch(void* const* d_in, const int* in_sizes, int n_in,
                              void* d_out, int out_size, void* d_ws, size_t ws_size,
                              hipStream_t stream) {
    const float* in = (const float*)d_in[0];
    float* out = (float*)d_out;
    const int nsamples = in_sizes[0] / (NF * ND);   // 16384
    ip_gram_kernel<<<nsamples / 4, 256, 0, stream>>>(in, out);
}

// Round 3
// 233.037 us; speedup vs baseline: 1.2681x; 1.0043x over previous
//
#include <hip/hip_runtime.h>

#define NF 64
#define ND 32
#define NPAIR 2016
#define KSTR 40                   // bf16 units per field row (80 B): keeps b128 16B-aligned, ~2-way banks
#define SAMP_BF (NF * KSTR)       // 2560 bf16 per (hi|lo) array per sample

typedef __attribute__((ext_vector_type(8))) short bf16x8;
typedef __attribute__((ext_vector_type(4))) float f32x4;

// 256 threads = 4 waves, one sample per wave. No __syncthreads: each wave
// writes and reads only its own LDS region.
__global__ __launch_bounds__(256, 4) void ip_gram_mfma(
    const float* __restrict__ in, float* __restrict__ out) {

    __shared__ unsigned short sh[4 * 2 * SAMP_BF];   // 40960 B -> 4 blocks/CU

    const int t = threadIdx.x;
    const int w = t >> 6;
    const int l = t & 63;
    const int s = blockIdx.x * 4 + w;

    unsigned short* __restrict__ xhi = sh + w * 2 * SAMP_BF;
    unsigned short* __restrict__ xlo = xhi + SAMP_BF;

    const float* src = in + (size_t)s * (NF * ND);

    // ---- stage: coalesced float4 loads, split fp32 -> bf16 hi + bf16 lo ----
    #pragma unroll
    for (int it = 0; it < 8; ++it) {
        int idx4 = l + (it << 6);           // float4 index 0..511
        float4 v = ((const float4*)src)[idx4];
        int f  = idx4 >> 3;                 // field
        int k0 = (idx4 & 7) << 2;           // k base (multiple of 4)
        float xv[4] = {v.x, v.y, v.z, v.w};
        ushort4 hv, lv;
        unsigned short* hp = (unsigned short*)&hv;
        unsigned short* lp = (unsigned short*)&lv;
        #pragma unroll
        for (int e = 0; e < 4; ++e) {
            unsigned xb = __builtin_bit_cast(unsigned, xv[e]);
            hp[e] = (unsigned short)(xb >> 16);                       // truncate -> hi
            float hf = __builtin_bit_cast(float, xb & 0xFFFF0000u);
            float lf = xv[e] - hf;                                     // exact
            lp[e] = (unsigned short)(__builtin_bit_cast(unsigned, lf) >> 16);
        }
        *(ushort4*)&xhi[f * KSTR + k0] = hv;   // 8-B aligned
        *(ushort4*)&xlo[f * KSTR + k0] = lv;
    }

    // ---- load MFMA fragments: blk r covers fields r*16..r*16+15 ----
    // lane element: X[r*16 + (l&15)][(l>>4)*8 .. +8]  (serves as BOTH A- and B-frag)
    const int q = l >> 4;
    const int m = l & 15;
    bf16x8 fhi[4], flo[4];
    #pragma unroll
    for (int r = 0; r < 4; ++r) {
        int off = (r * 16 + m) * KSTR + (q << 3);
        fhi[r] = *(const bf16x8*)&xhi[off];
        flo[r] = *(const bf16x8*)&xlo[off];
    }

    // ---- upper tiles: D = Xhi*Xhi^T + Xhi*Xlo^T + Xlo*Xhi^T, direct global stores ----
    float* dst = out + (size_t)s * NPAIR;
    #pragma unroll
    for (int ti = 0; ti < 4; ++ti) {
        #pragma unroll
        for (int tj = ti; tj < 4; ++tj) {
            f32x4 c = {0.f, 0.f, 0.f, 0.f};
            c = __builtin_amdgcn_mfma_f32_16x16x32_bf16(fhi[ti], fhi[tj], c, 0, 0, 0);
            c = __builtin_amdgcn_mfma_f32_16x16x32_bf16(fhi[ti], flo[tj], c, 0, 0, 0);
            c = __builtin_amdgcn_mfma_f32_16x16x32_bf16(flo[ti], fhi[tj], c, 0, 0, 0);
            // C/D layout: row i-part = q*4 + reg, col j-part = m
            int j = tj * 16 + m;
            #pragma unroll
            for (int r = 0; r < 4; ++r) {
                int i = ti * 16 + (q << 2) + r;
                if (ti < tj || j > i) {
                    int p = ((i * (127 - i)) >> 1) + j - i - 1;
                    dst[p] = c[r];
                }
            }
        }
    }
}

extern "C" void kernel_launch(void* const* d_in, const int* in_sizes, int n_in,
                              void* d_out, int out_size, void* d_ws, size_t ws_size,
                              hipStream_t stream) {
    const float* in = (const float*)d_in[0];
    float* out = (float*)d_out;
    const int nsamples = in_sizes[0] / (NF * ND);   // 16384
    ip_gram_mfma<<<nsamples / 4, 256, 0, stream>>>(in, out);
}